// Round 11
// baseline (653.731 us; speedup 1.0000x reference)
//
#include <hip/hip_runtime.h>
#include <hip/hip_bf16.h>
#include <stdint.h>

#define HORIZON 12

typedef __bf16 bf16x8 __attribute__((ext_vector_type(8)));
typedef float  f32x16 __attribute__((ext_vector_type(16)));
typedef float  f32x4v __attribute__((ext_vector_type(4)));

__device__ __forceinline__ unsigned short f2bf(float f) {
  union { float f; uint32_t u; } v; v.f = f;
  return (unsigned short)((v.u + 0x7FFFu + ((v.u >> 16) & 1u)) >> 16);
}
__device__ __forceinline__ float bf2f(unsigned short s) {
  union { uint32_t u; float f; } v; v.u = ((uint32_t)s) << 16;
  return v.f;
}

__device__ __forceinline__ float sigm(float x) { return 1.0f / (1.0f + __expf(-x)); }
__device__ __forceinline__ float tanh_fast(float x) { return 1.0f - 2.0f / (__expf(2.0f * x) + 1.0f); }

#define MFMA(a, b, c) __builtin_amdgcn_mfma_f32_32x32x16_bf16(a, b, c, 0, 0, 0)

// ---------- prep: cast weights to bf16 in K-major slab layout + bias combos ----------
// Wb: matrix m in {Wih0,Whh0,Wih1,Whh1,Wlin} at m*196608 els; slab k (K16 window):
// el = m*196608 + (k*rows + r)*16 + kk  (r = output row, kk = k within window).
// Bc: [brz 2x256][bzz 2x256][bin 2x256][bhn 2x256][blin 256] f32.
__global__ void prep(const float* __restrict__ wih, const float* __restrict__ whh,
                     const float* __restrict__ wlin, const float* __restrict__ bih,
                     const float* __restrict__ bhh, const float* __restrict__ blin,
                     unsigned short* __restrict__ Wb, float* __restrict__ Bc) {
  const int stride = gridDim.x * blockDim.x;
  for (int i = blockIdx.x * blockDim.x + threadIdx.x; i < 215296; i += stride) {
    if (i < 212992) {
      const int e = i << 2;
      const float* src; int m, rel;
      if (e < 196608)      { src = wih + e;             m = 0; rel = e; }
      else if (e < 393216) { src = whh + (e - 196608);  m = 1; rel = e - 196608; }
      else if (e < 589824) { src = wih + (e - 196608);  m = 2; rel = e - 393216; }
      else if (e < 786432) { src = whh + (e - 393216);  m = 3; rel = e - 589824; }
      else                 { src = wlin + (e - 786432); m = 4; rel = e - 786432; }
      const int rows = (m < 4) ? 768 : 256;
      const int r = rel >> 8, c = rel & 255;
      const float4 v = *(const float4*)src;
      unsigned short* dst = Wb + m * 196608 + ((c >> 4) * rows + r) * 16 + (c & 15);
      dst[0] = f2bf(v.x); dst[1] = f2bf(v.y); dst[2] = f2bf(v.z); dst[3] = f2bf(v.w);
    } else {
      const int t = i - 212992;
      float v;
      if (t < 512)       { const int l = t >> 8,        d = t & 255; v = bih[l*768+d]     + bhh[l*768+d]; }
      else if (t < 1024) { const int l = (t-512) >> 8,  d = t & 255; v = bih[l*768+256+d] + bhh[l*768+256+d]; }
      else if (t < 1536) { const int l = (t-1024) >> 8, d = t & 255; v = bih[l*768+512+d]; }
      else if (t < 2048) { const int l = (t-1536) >> 8, d = t & 255; v = bhh[l*768+512+d]; }
      else               { v = blin[t - 2048]; }
      Bc[t] = v;
    }
  }
}

// ---------- persistent fused decoder ----------
// 256 blocks x 512 threads; block owns batch stripe [b0, b0+64).
// D[row=batch][col=dim]: A = x/h bf16 from LDS (batch rows), B = W^T fragments
// streamed from global INTO REGISTERS per wave (wave owns dims w*32..+31).
// Round-10/11:
//  (1) per-t L2 WARMING: each block bulk-reads a 53KB slice of the 1.7MB
//      weight set (32 blocks/XCD cover it all) so pass loads hit L2 (~200cy)
//      instead of HBM (~900cy) — r5-r9 FETCH showed per-t weight eviction
//      by the y-stream; traffic is trivial, chain latency was the killer.
//      (r11 fix: asm sink takes a SCALAR — XOR-fold the uint4s first.)
//  (2) depth-2 pipeline on 3-stream passes: f[3][3]=36 frag VGPR (fits the
//      128-VGPR half of the 256-reg budget; r7-r9 deeper attempts spilled).
//  (3) no SC transpose: dim is on LANES here, so direct fp32 y-stores are
//      128B-contiguous per 32-lane group. -32KB LDS, -2 barriers/t.
// C/D: col = lane&31 = dim, row = (reg&3)+8*(reg>>2)+4*(lane>>5) = batch row.
// h state lives ONLY as bf16 in LDS (owner-exclusive RMW in epilogue).
// LDS x/h: [64 rows][256 dims] bf16, granule g at slot g^(row&31) (conflict-free).
__global__ __launch_bounds__(512) __attribute__((amdgpu_waves_per_eu(2, 2)))
void rnn_persist(
    const float* __restrict__ y0, const float* __restrict__ h0f,
    const unsigned short* __restrict__ Wb, const float* __restrict__ Bc,
    float* __restrict__ out) {
  extern __shared__ char lds[];
  char* XB = lds;            // 32 KB bf16 [64][256]
  char* H0 = lds + 32768;    // 32 KB
  char* H1 = lds + 65536;    // 32 KB

  const int tid = threadIdx.x;
  const int w   = tid >> 6;
  const int l   = tid & 63;
  const int l31 = l & 31;
  const int hi  = l >> 5;
  const int b0  = blockIdx.x * 64;
  const int dw  = w * 32 + l31;          // this lane's output dim
  const int sub2 = (l31 & 7) * 2;        // byte pos of dim within its granule
  const int gdw  = w * 4 + (l31 >> 3);   // dim-granule index of dw

  f32x16 Ar[2], Az[2], Ai[2], Ah[2];

  // ---- init XB = bf16(y0 stripe), swizzled ----
#pragma unroll
  for (int rr = 0; rr < 8; ++rr) {
    const int idx = rr * 2048 + tid * 4;
    const int row = idx >> 8, dd = idx & 255;
    const f32x4v v = __builtin_nontemporal_load(
        (const f32x4v*)(y0 + (size_t)(b0 + row) * 256 + dd));
    ushort4 o; o.x = f2bf(v.x); o.y = f2bf(v.y); o.z = f2bf(v.z); o.w = f2bf(v.w);
    *(ushort4*)(XB + row * 512 + (((dd >> 3) ^ (row & 31)) << 4) + (dd & 7) * 2) = o;
  }

  // ---- init H0/H1 = bf16(h0 stripes), swizzled ----
  auto initH = [&](const float* src, char* Hl) {
#pragma unroll
    for (int rr = 0; rr < 8; ++rr) {
      const int idx = rr * 2048 + tid * 4;
      const int row = idx >> 8, dd = idx & 255;
      const f32x4v v = __builtin_nontemporal_load(
          (const f32x4v*)(src + (size_t)(b0 + row) * 256 + dd));
      ushort4 o; o.x = f2bf(v.x); o.y = f2bf(v.y); o.z = f2bf(v.z); o.w = f2bf(v.w);
      *(ushort4*)(Hl + row * 512 + (((dd >> 3) ^ (row & 31)) << 4) + (dd & 7) * 2) = o;
    }
  };
  initH(h0f, H0);
  initH(h0f + (size_t)16384 * 256, H1);
  __syncthreads();

  const char* Wp = (const char*)Wb;

  auto zacc = [&](f32x16 (&A)[2]) {
#pragma unroll
    for (int ct = 0; ct < 2; ++ct)
#pragma unroll
      for (int r = 0; r < 16; ++r) A[ct][r] = 0.0f;
  };

  // one 3-stream pass: 16 K16 iters, depth-2 rotating pipeline (3 buffers),
  // pointer-bump + asm-pin addressing (never materialize base+k*stride).
  auto passG3 = [&](const char* As, size_t mBase,
                    f32x16 (&G0)[2], f32x16 (&G1)[2], f32x16 (&G2)[2]) {
    const char* q0 = Wp + mBase + (size_t)(0 * 256 + dw) * 32 + hi * 16;
    const char* q1 = Wp + mBase + (size_t)(1 * 256 + dw) * 32 + hi * 16;
    const char* q2 = Wp + mBase + (size_t)(2 * 256 + dw) * 32 + hi * 16;
    bf16x8 f[3][3];
#define LOADSET3(buf)                                          \
    f[buf][0] = *(const bf16x8*)q0; q0 += 24576;               \
    f[buf][1] = *(const bf16x8*)q1; q1 += 24576;               \
    f[buf][2] = *(const bf16x8*)q2; q2 += 24576;               \
    asm volatile("" : "+v"(q0), "+v"(q1), "+v"(q2));
    LOADSET3(0)
    LOADSET3(1)
#pragma unroll
    for (int k = 0; k < 16; ++k) {
      if (k < 14) { LOADSET3((k + 2) % 3) }
      const int cur = k % 3;
      const int go = ((2 * k + hi) ^ l31) << 4;
      const bf16x8 a0 = *(const bf16x8*)(As + l31 * 512 + go);
      const bf16x8 a1 = *(const bf16x8*)(As + (32 + l31) * 512 + go);
      __builtin_amdgcn_s_setprio(1);
      G0[0] = MFMA(a0, f[cur][0], G0[0]);
      G1[0] = MFMA(a0, f[cur][1], G1[0]);
      G2[0] = MFMA(a0, f[cur][2], G2[0]);
      G0[1] = MFMA(a1, f[cur][0], G0[1]);
      G1[1] = MFMA(a1, f[cur][1], G1[1]);
      G2[1] = MFMA(a1, f[cur][2], G2[1]);
      __builtin_amdgcn_s_setprio(0);
    }
#undef LOADSET3
  };

  auto passLin = [&](const char* Hs, size_t mL) {
    const char* pL = Wp + mL + (size_t)dw * 32 + hi * 16;
    bf16x8 f[3];
    f[0] = *(const bf16x8*)pL; pL += 8192;
    asm volatile("" : "+v"(pL));
    f[1] = *(const bf16x8*)pL; pL += 8192;
    asm volatile("" : "+v"(pL));
#pragma unroll
    for (int k = 0; k < 16; ++k) {
      if (k < 14) {
        f[(k + 2) % 3] = *(const bf16x8*)pL; pL += 8192;
        asm volatile("" : "+v"(pL));
      }
      const int cur = k % 3;
      const int go = ((2 * k + hi) ^ l31) << 4;
      const bf16x8 a0 = *(const bf16x8*)(Hs + l31 * 512 + go);
      const bf16x8 a1 = *(const bf16x8*)(Hs + (32 + l31) * 512 + go);
      __builtin_amdgcn_s_setprio(1);
      Ar[0] = MFMA(a0, f[cur], Ar[0]);
      Ar[1] = MFMA(a1, f[cur], Ar[1]);
      __builtin_amdgcn_s_setprio(0);
    }
  };

  // GRU epilogue: owner-exclusive bf16 RMW of h in LDS, gates in fp32
  auto epi = [&](int L, char* Hl) {
    const float brz = Bc[L * 256 + dw];
    const float bzz = Bc[512 + L * 256 + dw];
    const float bin = Bc[1024 + L * 256 + dw];
    const float bhn = Bc[1536 + L * 256 + dw];
#pragma unroll
    for (int ct = 0; ct < 2; ++ct) {
#pragma unroll
      for (int reg = 0; reg < 16; ++reg) {
        const int rl = (reg & 3) + 8 * (reg >> 2) + 4 * hi;
        unsigned short* hp =
            (unsigned short*)(Hl + (ct * 32 + rl) * 512 + ((gdw ^ rl) << 4) + sub2);
        const float hold = bf2f(*hp);
        const float rg = sigm(Ar[ct][reg] + brz);
        const float zg = sigm(Az[ct][reg] + bzz);
        const float nn = tanh_fast(Ai[ct][reg] + bin + rg * (Ah[ct][reg] + bhn));
        const float hv = (1.0f - zg) * nn + zg * hold;
        *hp = f2bf(hv);
      }
    }
  };

#pragma unroll 1
  for (int t = 0; t < HORIZON; ++t) {
    // ---- L2 warm: this block's 53248B slice of the weight set (slot = bid/8,
    // 32 slots cover 1.7MB; bid%8 = XCD round-robin heuristic — perf only).
    // XOR-fold each uint4 to a scalar for the asm keep-alive sink. ----
    {
      const char* wbase = Wp + (size_t)(blockIdx.x >> 3) * 53248;
      uint32_t acc = 0;
#pragma unroll
      for (int j = 0; j < 7; ++j) {
        const int i = j * 512 + tid;
        if (j < 6 || i < 3328) {
          const uint4 wv = *(const uint4*)(wbase + (size_t)i * 16);
          acc ^= wv.x ^ wv.y ^ wv.z ^ wv.w;
        }
      }
      asm volatile("" :: "v"(acc));
    }

    // layer 0: gi(XB) then gh(H0-old), 3-stream passes
    zacc(Ar); zacc(Az); zacc(Ai); zacc(Ah);
    passG3(XB, 0,      Ar, Az, Ai);     // x @ {Wr,Wz,Wn}^T
    passG3(H0, 393216, Ar, Az, Ah);     // h @ {Ur,Uz,Un}^T
    __syncthreads();            // all pass reads of XB/H0-old done
    epi(0, H0);
    __syncthreads();            // H0-new visible
    // layer 1: gi(H0-new) then gh(H1-old)
    zacc(Ar); zacc(Az); zacc(Ai); zacc(Ah);
    passG3(H0, 786432,  Ar, Az, Ai);
    passG3(H1, 1179648, Ar, Az, Ah);
    __syncthreads();
    epi(1, H1);
    __syncthreads();
    // output linear
    zacc(Ar);
    passLin(H1, 1572864);
    // direct epilogue: fp32 y NT-stores (128B-contiguous per 32-lane group)
    // + bf16 next-x into XB (owner-exclusive, swizzled)
    {
      const float bl = Bc[2048 + dw];
      float* og = out + ((size_t)t * 16384 + b0) * 256;
#pragma unroll
      for (int ct = 0; ct < 2; ++ct) {
#pragma unroll
        for (int reg = 0; reg < 16; ++reg) {
          const int rl = (reg & 3) + 8 * (reg >> 2) + 4 * hi;
          const int row = ct * 32 + rl;
          const float y = Ar[ct][reg] + bl;
          __builtin_nontemporal_store(y, og + (size_t)row * 256 + dw);
          *(unsigned short*)(XB + row * 512 + ((gdw ^ (row & 31)) << 4) + sub2) = f2bf(y);
        }
      }
    }
    __syncthreads();            // XB/H visible for next t
  }
}

// ---------- launch ----------
extern "C" void kernel_launch(void* const* d_in, const int* in_sizes, int n_in,
                              void* d_out, int out_size, void* d_ws, size_t ws_size,
                              hipStream_t stream) {
  (void)in_sizes; (void)n_in; (void)out_size; (void)ws_size;
  const float* y0   = (const float*)d_in[0];
  const float* h0   = (const float*)d_in[1];
  const float* wih  = (const float*)d_in[2];
  const float* whh  = (const float*)d_in[3];
  const float* bih  = (const float*)d_in[4];
  const float* bhh  = (const float*)d_in[5];
  const float* wlin = (const float*)d_in[6];
  const float* blin = (const float*)d_in[7];
  float* out = (float*)d_out;

  unsigned short* Wb = (unsigned short*)d_ws;            // 851968 bf16 els
  float* Bc = (float*)((char*)d_ws + 1703936);           // 2304 f32

  static bool attr_done = false;
  if (!attr_done) {
    hipFuncSetAttribute((const void*)rnn_persist,
                        hipFuncAttributeMaxDynamicSharedMemorySize, 98304);
    attr_done = true;
  }

  prep<<<512, 256, 0, stream>>>(wih, whh, wlin, bih, bhh, blin, Wb, Bc);
  rnn_persist<<<256, 512, 98304, stream>>>(y0, h0, Wb, Bc, out);
}

// Round 12
// 649.110 us; speedup vs baseline: 1.0071x; 1.0071x over previous
//
#include <hip/hip_runtime.h>
#include <hip/hip_bf16.h>
#include <stdint.h>

#define HORIZON 12

typedef __bf16 bf16x8 __attribute__((ext_vector_type(8)));
typedef float  f32x16 __attribute__((ext_vector_type(16)));
typedef float  f32x4v __attribute__((ext_vector_type(4)));

__device__ __forceinline__ unsigned short f2bf(float f) {
  union { float f; uint32_t u; } v; v.f = f;
  return (unsigned short)((v.u + 0x7FFFu + ((v.u >> 16) & 1u)) >> 16);
}
__device__ __forceinline__ float bf2f(unsigned short s) {
  union { uint32_t u; float f; } v; v.u = ((uint32_t)s) << 16;
  return v.f;
}

__device__ __forceinline__ float sigm(float x) { return 1.0f / (1.0f + __expf(-x)); }
__device__ __forceinline__ float tanh_fast(float x) { return 1.0f - 2.0f / (__expf(2.0f * x) + 1.0f); }

#define MFMA(a, b, c) __builtin_amdgcn_mfma_f32_32x32x16_bf16(a, b, c, 0, 0, 0)

// ---------- prep: cast weights to bf16 in K-major slab layout + bias combos ----------
// Wb: matrix m in {Wih0,Whh0,Wih1,Whh1,Wlin} at m*196608 els; slab k (K16 window):
// el = m*196608 + (k*rows + r)*16 + kk  (r = output row, kk = k within window).
// Bc: [brz 2x256][bzz 2x256][bin 2x256][bhn 2x256][blin 256] f32.
__global__ void prep(const float* __restrict__ wih, const float* __restrict__ whh,
                     const float* __restrict__ wlin, const float* __restrict__ bih,
                     const float* __restrict__ bhh, const float* __restrict__ blin,
                     unsigned short* __restrict__ Wb, float* __restrict__ Bc) {
  const int stride = gridDim.x * blockDim.x;
  for (int i = blockIdx.x * blockDim.x + threadIdx.x; i < 215296; i += stride) {
    if (i < 212992) {
      const int e = i << 2;
      const float* src; int m, rel;
      if (e < 196608)      { src = wih + e;             m = 0; rel = e; }
      else if (e < 393216) { src = whh + (e - 196608);  m = 1; rel = e - 196608; }
      else if (e < 589824) { src = wih + (e - 196608);  m = 2; rel = e - 393216; }
      else if (e < 786432) { src = whh + (e - 393216);  m = 3; rel = e - 589824; }
      else                 { src = wlin + (e - 786432); m = 4; rel = e - 786432; }
      const int rows = (m < 4) ? 768 : 256;
      const int r = rel >> 8, c = rel & 255;
      const float4 v = *(const float4*)src;
      unsigned short* dst = Wb + m * 196608 + ((c >> 4) * rows + r) * 16 + (c & 15);
      dst[0] = f2bf(v.x); dst[1] = f2bf(v.y); dst[2] = f2bf(v.z); dst[3] = f2bf(v.w);
    } else {
      const int t = i - 212992;
      float v;
      if (t < 512)       { const int l = t >> 8,        d = t & 255; v = bih[l*768+d]     + bhh[l*768+d]; }
      else if (t < 1024) { const int l = (t-512) >> 8,  d = t & 255; v = bih[l*768+256+d] + bhh[l*768+256+d]; }
      else if (t < 1536) { const int l = (t-1024) >> 8, d = t & 255; v = bih[l*768+512+d]; }
      else if (t < 2048) { const int l = (t-1536) >> 8, d = t & 255; v = bhh[l*768+512+d]; }
      else               { v = blin[t - 2048]; }
      Bc[t] = v;
    }
  }
}

// ---------- persistent fused decoder ----------
// 256 blocks x 512 threads; block owns batch stripe [b0, b0+64).
// D[row=batch][col=dim]: A = x/h bf16 from LDS, B = W^T fragments streamed
// from global into registers per wave (wave owns dims w*32..+31).
// Round-12: TWO-PHASE GATES. Phase A accumulates S_r,S_z (64 acc regs) over
// {x@Wr, x@Wz, h@Ur, h@Uz}; its epilogue packs r,z = sigm(.) as bf16 pairs
// in 32 VGPRs (thread-local: lane's C/D elements ARE the ones it needs).
// Phase B reuses the same 64-reg acc for I_n,H_n; epilogue does gate math +
// owner-exclusive bf16 h RMW in LDS. Halving acc 128->64 frees headroom for
// a DEPTH-3 fragment pipeline (f[4][4]=64 VGPR) without spills (r7-r11: any
// pipeline next to a 128-reg acc spilled). Exposed latency ~600/3=200cy/iter.
// C/D: col = lane&31 = dim, row = (reg&3)+8*(reg>>2)+4*(lane>>5) = batch row.
// LDS x/h: [64 rows][256 dims] bf16, granule g at slot g^(row&31) (conflict-free).
__global__ __launch_bounds__(512) __attribute__((amdgpu_waves_per_eu(2, 2)))
void rnn_persist(
    const float* __restrict__ y0, const float* __restrict__ h0f,
    const unsigned short* __restrict__ Wb, const float* __restrict__ Bc,
    float* __restrict__ out) {
  extern __shared__ char lds[];
  char* XB = lds;            // 32 KB bf16 [64][256]
  char* H0 = lds + 32768;    // 32 KB
  char* H1 = lds + 65536;    // 32 KB

  const int tid = threadIdx.x;
  const int w   = tid >> 6;
  const int l   = tid & 63;
  const int l31 = l & 31;
  const int hi  = l >> 5;
  const int b0  = blockIdx.x * 64;
  const int dw  = w * 32 + l31;          // this lane's output dim
  const int sub2 = (l31 & 7) * 2;        // byte pos of dim within its granule
  const int gdw  = w * 4 + (l31 >> 3);   // dim-granule index of dw

  f32x16 A0[2], A1[2];                   // 64-reg accumulator (reused per phase)
  uint32_t rp[2][8], zp[2][8];           // packed bf16 r,z (32 regs)

  // ---- init XB = bf16(y0 stripe), swizzled ----
#pragma unroll
  for (int rr = 0; rr < 8; ++rr) {
    const int idx = rr * 2048 + tid * 4;
    const int row = idx >> 8, dd = idx & 255;
    const f32x4v v = __builtin_nontemporal_load(
        (const f32x4v*)(y0 + (size_t)(b0 + row) * 256 + dd));
    ushort4 o; o.x = f2bf(v.x); o.y = f2bf(v.y); o.z = f2bf(v.z); o.w = f2bf(v.w);
    *(ushort4*)(XB + row * 512 + (((dd >> 3) ^ (row & 31)) << 4) + (dd & 7) * 2) = o;
  }

  // ---- init H0/H1 = bf16(h0 stripes), swizzled ----
  auto initH = [&](const float* src, char* Hl) {
#pragma unroll
    for (int rr = 0; rr < 8; ++rr) {
      const int idx = rr * 2048 + tid * 4;
      const int row = idx >> 8, dd = idx & 255;
      const f32x4v v = __builtin_nontemporal_load(
          (const f32x4v*)(src + (size_t)(b0 + row) * 256 + dd));
      ushort4 o; o.x = f2bf(v.x); o.y = f2bf(v.y); o.z = f2bf(v.z); o.w = f2bf(v.w);
      *(ushort4*)(Hl + row * 512 + (((dd >> 3) ^ (row & 31)) << 4) + (dd & 7) * 2) = o;
    }
  };
  initH(h0f, H0);
  initH(h0f + (size_t)16384 * 256, H1);
  __syncthreads();

  const char* Wp = (const char*)Wb;

  auto zacc = [&]() {
#pragma unroll
    for (int ct = 0; ct < 2; ++ct)
#pragma unroll
      for (int r = 0; r < 16; ++r) { A0[ct][r] = 0.0f; A1[ct][r] = 0.0f; }
  };

  // Phase-A pass: 4 streams {x@g0, x@g1, h@g0, h@g1}, depth-3 pipeline.
  // gsel: byte offset of the first gate row-block (0 for r/z pair, 512*32 for n).
  auto passA = [&](const char* Xs, const char* Hs, size_t mI, size_t mH) {
    const char* q0 = Wp + mI + (size_t)(0 * 256 + dw) * 32 + hi * 16;
    const char* q1 = Wp + mI + (size_t)(1 * 256 + dw) * 32 + hi * 16;
    const char* q2 = Wp + mH + (size_t)(0 * 256 + dw) * 32 + hi * 16;
    const char* q3 = Wp + mH + (size_t)(1 * 256 + dw) * 32 + hi * 16;
    bf16x8 f[4][4];
#define LOADSET4(buf)                                          \
    f[buf][0] = *(const bf16x8*)q0; q0 += 24576;               \
    f[buf][1] = *(const bf16x8*)q1; q1 += 24576;               \
    f[buf][2] = *(const bf16x8*)q2; q2 += 24576;               \
    f[buf][3] = *(const bf16x8*)q3; q3 += 24576;               \
    asm volatile("" : "+v"(q0), "+v"(q1), "+v"(q2), "+v"(q3));
    LOADSET4(0)
    LOADSET4(1)
    LOADSET4(2)
#pragma unroll
    for (int k = 0; k < 16; ++k) {
      if (k < 13) { LOADSET4((k + 3) % 4) }
      const int cur = k % 4;
      const int go = ((2 * k + hi) ^ l31) << 4;
      const bf16x8 aX0 = *(const bf16x8*)(Xs + l31 * 512 + go);
      const bf16x8 aH0 = *(const bf16x8*)(Hs + l31 * 512 + go);
      const bf16x8 aX1 = *(const bf16x8*)(Xs + (32 + l31) * 512 + go);
      const bf16x8 aH1 = *(const bf16x8*)(Hs + (32 + l31) * 512 + go);
      __builtin_amdgcn_s_setprio(1);
      A0[0] = MFMA(aX0, f[cur][0], A0[0]);
      A1[0] = MFMA(aX0, f[cur][1], A1[0]);
      A0[1] = MFMA(aX1, f[cur][0], A0[1]);
      A1[1] = MFMA(aX1, f[cur][1], A1[1]);
      A0[0] = MFMA(aH0, f[cur][2], A0[0]);
      A1[0] = MFMA(aH0, f[cur][3], A1[0]);
      A0[1] = MFMA(aH1, f[cur][2], A0[1]);
      A1[1] = MFMA(aH1, f[cur][3], A1[1]);
      __builtin_amdgcn_s_setprio(0);
    }
#undef LOADSET4
  };

  // Phase-B pass: 2 streams {x@n, h@n}, depth-3 pipeline.
  auto passB = [&](const char* Xs, const char* Hs, size_t mI, size_t mH) {
    const char* q0 = Wp + mI + (size_t)(2 * 256 + dw) * 32 + hi * 16;
    const char* q1 = Wp + mH + (size_t)(2 * 256 + dw) * 32 + hi * 16;
    bf16x8 f[4][2];
#define LOADSET2(buf)                                          \
    f[buf][0] = *(const bf16x8*)q0; q0 += 24576;               \
    f[buf][1] = *(const bf16x8*)q1; q1 += 24576;               \
    asm volatile("" : "+v"(q0), "+v"(q1));
    LOADSET2(0)
    LOADSET2(1)
    LOADSET2(2)
#pragma unroll
    for (int k = 0; k < 16; ++k) {
      if (k < 13) { LOADSET2((k + 3) % 4) }
      const int cur = k % 4;
      const int go = ((2 * k + hi) ^ l31) << 4;
      const bf16x8 aX0 = *(const bf16x8*)(Xs + l31 * 512 + go);
      const bf16x8 aH0 = *(const bf16x8*)(Hs + l31 * 512 + go);
      const bf16x8 aX1 = *(const bf16x8*)(Xs + (32 + l31) * 512 + go);
      const bf16x8 aH1 = *(const bf16x8*)(Hs + (32 + l31) * 512 + go);
      __builtin_amdgcn_s_setprio(1);
      A0[0] = MFMA(aX0, f[cur][0], A0[0]);
      A1[0] = MFMA(aH0, f[cur][1], A1[0]);
      A0[1] = MFMA(aX1, f[cur][0], A0[1]);
      A1[1] = MFMA(aH1, f[cur][1], A1[1]);
      __builtin_amdgcn_s_setprio(0);
    }
#undef LOADSET2
  };

  auto passLin = [&](const char* Hs, size_t mL) {
    const char* pL = Wp + mL + (size_t)dw * 32 + hi * 16;
    bf16x8 f[4];
#define LOADSET1(buf)                                          \
    f[buf] = *(const bf16x8*)pL; pL += 8192;                   \
    asm volatile("" : "+v"(pL));
    LOADSET1(0)
    LOADSET1(1)
    LOADSET1(2)
#pragma unroll
    for (int k = 0; k < 16; ++k) {
      if (k < 13) { LOADSET1((k + 3) % 4) }
      const int cur = k % 4;
      const int go = ((2 * k + hi) ^ l31) << 4;
      const bf16x8 a0 = *(const bf16x8*)(Hs + l31 * 512 + go);
      const bf16x8 a1 = *(const bf16x8*)(Hs + (32 + l31) * 512 + go);
      __builtin_amdgcn_s_setprio(1);
      A0[0] = MFMA(a0, f[cur], A0[0]);
      A0[1] = MFMA(a1, f[cur], A0[1]);
      __builtin_amdgcn_s_setprio(0);
    }
#undef LOADSET1
  };

  // epiA: r,z = sigm(S + bias), pack bf16 pairs into rp/zp (thread-local).
  auto epiA = [&](int L) {
    const float brz = Bc[L * 256 + dw];
    const float bzz = Bc[512 + L * 256 + dw];
#pragma unroll
    for (int ct = 0; ct < 2; ++ct) {
#pragma unroll
      for (int j = 0; j < 8; ++j) {
        const float r0 = sigm(A0[ct][2 * j]     + brz);
        const float r1 = sigm(A0[ct][2 * j + 1] + brz);
        const float z0 = sigm(A1[ct][2 * j]     + bzz);
        const float z1 = sigm(A1[ct][2 * j + 1] + bzz);
        rp[ct][j] = (uint32_t)f2bf(r0) | ((uint32_t)f2bf(r1) << 16);
        zp[ct][j] = (uint32_t)f2bf(z0) | ((uint32_t)f2bf(z1) << 16);
      }
    }
  };

  // epiB: n = tanh(In + bin + r*(Hn + bhn)); h = (1-z)n + z*h_old (LDS RMW).
  auto epiB = [&](int L, char* Hl) {
    const float bin = Bc[1024 + L * 256 + dw];
    const float bhn = Bc[1536 + L * 256 + dw];
#pragma unroll
    for (int ct = 0; ct < 2; ++ct) {
#pragma unroll
      for (int j = 0; j < 8; ++j) {
#pragma unroll
        for (int e = 0; e < 2; ++e) {
          const int reg = 2 * j + e;
          const float rr = bf2f((unsigned short)(e ? (rp[ct][j] >> 16) : (rp[ct][j] & 0xFFFF)));
          const float zz = bf2f((unsigned short)(e ? (zp[ct][j] >> 16) : (zp[ct][j] & 0xFFFF)));
          const int rl = (reg & 3) + 8 * (reg >> 2) + 4 * hi;
          unsigned short* hp =
              (unsigned short*)(Hl + (ct * 32 + rl) * 512 + ((gdw ^ rl) << 4) + sub2);
          const float hold = bf2f(*hp);
          const float nn = tanh_fast(A0[ct][reg] + bin + rr * (A1[ct][reg] + bhn));
          const float hv = (1.0f - zz) * nn + zz * hold;
          *hp = f2bf(hv);
        }
      }
    }
  };

#pragma unroll 1
  for (int t = 0; t < HORIZON; ++t) {
    // ---- layer 0 ----
    zacc();
    passA(XB, H0, 0, 393216);      // S_r,S_z
    epiA(0);
    zacc();
    passB(XB, H0, 0, 393216);      // I_n,H_n
    __syncthreads();               // all waves done reading H0-old
    epiB(0, H0);
    __syncthreads();               // H0-new visible
    // ---- layer 1 ----
    zacc();
    passA(H0, H1, 786432, 1179648);
    epiA(1);
    zacc();
    passB(H0, H1, 786432, 1179648);
    __syncthreads();
    epiB(1, H1);
    __syncthreads();
    // ---- output linear ----
#pragma unroll
    for (int ct = 0; ct < 2; ++ct)
#pragma unroll
      for (int r = 0; r < 16; ++r) A0[ct][r] = 0.0f;
    passLin(H1, 1572864);
    // direct epilogue: fp32 y NT-stores (128B-contiguous per 32-lane group)
    // + bf16 next-x into XB (owner-exclusive, swizzled)
    {
      const float bl = Bc[2048 + dw];
      float* og = out + ((size_t)t * 16384 + b0) * 256;
#pragma unroll
      for (int ct = 0; ct < 2; ++ct) {
#pragma unroll
        for (int reg = 0; reg < 16; ++reg) {
          const int rl = (reg & 3) + 8 * (reg >> 2) + 4 * hi;
          const int row = ct * 32 + rl;
          const float y = A0[ct][reg] + bl;
          __builtin_nontemporal_store(y, og + (size_t)row * 256 + dw);
          *(unsigned short*)(XB + row * 512 + ((gdw ^ (row & 31)) << 4) + sub2) = f2bf(y);
        }
      }
    }
    __syncthreads();               // XB visible for next t
  }
}

// ---------- launch ----------
extern "C" void kernel_launch(void* const* d_in, const int* in_sizes, int n_in,
                              void* d_out, int out_size, void* d_ws, size_t ws_size,
                              hipStream_t stream) {
  (void)in_sizes; (void)n_in; (void)out_size; (void)ws_size;
  const float* y0   = (const float*)d_in[0];
  const float* h0   = (const float*)d_in[1];
  const float* wih  = (const float*)d_in[2];
  const float* whh  = (const float*)d_in[3];
  const float* bih  = (const float*)d_in[4];
  const float* bhh  = (const float*)d_in[5];
  const float* wlin = (const float*)d_in[6];
  const float* blin = (const float*)d_in[7];
  float* out = (float*)d_out;

  unsigned short* Wb = (unsigned short*)d_ws;            // 851968 bf16 els
  float* Bc = (float*)((char*)d_ws + 1703936);           // 2304 f32

  static bool attr_done = false;
  if (!attr_done) {
    (void)hipFuncSetAttribute((const void*)rnn_persist,
                              hipFuncAttributeMaxDynamicSharedMemorySize, 98304);
    attr_done = true;
  }

  prep<<<512, 256, 0, stream>>>(wih, whh, wlin, bih, bhh, blin, Wb, Bc);
  rnn_persist<<<256, 512, 98304, stream>>>(y0, h0, Wb, Bc, out);
}